// Round 5
// baseline (158.798 us; speedup 1.0000x reference)
//
#include <hip/hip_runtime.h>
#include <hip/hip_bf16.h>
#include <cstddef>

#define G_   2048
#define NPG_ 512
#define CPG_ 128
#define CPG2_ 32

// output layout (floats): z_what[G,64] | z_mask[G,64] | mu[G,128] | sigma[G,128] | f[G,256]
#define OFF_ZW 0
#define OFF_ZM (G_*64)
#define OFF_MU (2*G_*64)
#define OFF_SG (2*G_*64 + G_*128)
#define OFF_F  (2*G_*64 + 2*G_*128)

typedef __attribute__((ext_vector_type(8))) short bf16x8;
typedef __attribute__((ext_vector_type(4))) float f32x4;
typedef _Float16 f16x2 __attribute__((ext_vector_type(2)));

__device__ __forceinline__ float celu_f(float x)     { return x > 0.f ? x : __expf(x) - 1.f; }
__device__ __forceinline__ float softplus_f(float x) { return fmaxf(x, 0.f) + __logf(1.f + __expf(-fabsf(x))); }
// fast RNE fp32->bf16 (finite inputs): identical result to __float2bfloat16
__device__ __forceinline__ unsigned short f2bf(float x) {
    unsigned u = __float_as_uint(x);
    u += 0x7FFFu + ((u >> 16) & 1u);
    return (unsigned short)(u >> 16);
}
__device__ __forceinline__ unsigned pack2(float a, float b) {   // bf16(a) | bf16(b)<<16
    unsigned ua = __float_as_uint(a); ua += 0x7FFFu + ((ua >> 16) & 1u);
    unsigned ub = __float_as_uint(b); ub += 0x7FFFu + ((ub >> 16) & 1u);
    return (ua >> 16) | (ub & 0xFFFF0000u);
}
// 8B-aligned bf16x8 LDS load (for odd-16B row strides)
__device__ __forceinline__ bf16x8 ldb8(const unsigned short* p) {
    union { uint2 u[2]; bf16x8 v; } x;
    x.u[0] = *(const uint2*)p;
    x.u[1] = *(const uint2*)(p + 4);
    return x.v;
}

// ---------------- prep: transposed, zero-K-padded bf16 weight copies in ws ----------------
__global__ void k_prep(const float* __restrict__ W2l, const float* __restrict__ W2g,
                       const float* __restrict__ W3l, const float* __restrict__ W3g,
                       const float* __restrict__ Wlin, const float* __restrict__ W1g,
                       unsigned short* __restrict__ w2lT, unsigned short* __restrict__ w2gT,
                       unsigned short* __restrict__ w3lT, unsigned short* __restrict__ w3gT,
                       unsigned short* __restrict__ wlinT, unsigned short* __restrict__ w1gT)
{
    const int tid = blockIdx.x*256 + threadIdx.x, stride = gridDim.x*256;
    for (int i = tid; i < 64*64; i += stride) {          // W2l [35,64] -> [ch][k=64pad]
        const int ch = i >> 6, k = i & 63;
        w2lT[i] = f2bf(k < 35 ? W2l[k*64 + ch] : 0.f);
    }
    for (int i = tid; i < 128*64; i += stride) {         // W2g [64,128] -> [ch][k]
        const int ch = i >> 6, k = i & 63;
        w2gT[i] = f2bf(W2g[k*128 + ch]);
    }
    for (int i = tid; i < 128*160; i += stride) {        // W3l [131,128] -> [ch][k=160pad]
        const int ch = i / 160, k = i % 160;
        w3lT[i] = f2bf(k < 131 ? W3l[k*128 + ch] : 0.f);
    }
    for (int i = tid; i < 256*128; i += stride) {        // W3g [128,256] -> [ch][k]
        const int ch = i >> 7, k = i & 127;
        w3gT[i] = f2bf(W3g[k*256 + ch]);
    }
    for (int i = tid; i < 256*256; i += stride) {        // Wlin [256,256] -> [ch][k]
        const int ch = i >> 8, k = i & 255;
        wlinT[i] = f2bf(Wlin[k*256 + ch]);
    }
    for (int i = tid; i < 32*40; i += stride) {          // W1g [16,32] -> [ch][k=40pad]
        const int ch = i / 40, k = i % 40;
        w1gT[i] = f2bf(k < 16 ? W1g[k*32 + ch] : 0.f);
    }
}

// ============== fused conv1+conv2+conv3local+mean: TWO glimpses per block ==============
// The back-half is software-pipelined A/B: each phase pairs glimpse-A store/fill work
// with glimpse-B MFMA work (or vice versa), halving barriers/glimpse (14 for 2 glimpses)
// and doubling per-phase independent ILP. Front-end phases split duties: threads 0-127
// handle glimpse A's per-cluster work, 128-255 glimpse B's.
// LDS 54016 B -> 3 blocks/CU. Overlay map (byte offsets):
//  front: hp4 uint4[2][2][512] @0 (32768) | aggT us[2][128][36] @32768 (18432)
//         | cnt int[2][128] @51200 | ctr @52224 | cnti int[2][32] @53248 | wtot[2] @53504
//  mid:   xs16 us[2][128][72] @0 (36864) | sT us[2][32][132] @36864 (16896)
//  late:  HT us[2][64][136] @0 (34816) -> xs3 us[2][32][168] @0 (21504)
//         agg2 us[2][32][72] @36864 (9216) -> red f32[2][128][9] @36864 (9216)
//  fixed: invc f32[2][32] @53760 (survives front->segsum)
__global__ __launch_bounds__(256, 3) void k_fused(
    const float* __restrict__ rgb, const float* __restrict__ pos, const float* __restrict__ pos1,
    const float* __restrict__ pos2, const int* __restrict__ idx0, const int* __restrict__ idx1,
    const float* __restrict__ W1l, const float* __restrict__ b1l,
    const unsigned short* __restrict__ w1gT, const float* __restrict__ b1g,
    const unsigned short* __restrict__ w2lT, const float* __restrict__ b2l,
    const unsigned short* __restrict__ w2gT, const float* __restrict__ b2g,
    const unsigned short* __restrict__ w3lT, const float* __restrict__ b3l,
    unsigned short* __restrict__ aggws)
{
    const int g0 = blockIdx.x * 2, t = threadIdx.x;
    const int lane = t & 63, wv = t >> 6;
    const int lr = lane & 15, quad = lane >> 4;
    const int myg = t >> 7;          // glimpse this thread serves for per-cluster-L1 duties
    const int th  = t & 127;         // cluster index within that glimpse

    __shared__ __align__(16) unsigned char smem[54016];
    uint4* const hp4 = (uint4*)smem;                                // [2][2][512] uint4
    unsigned short* const aggT = (unsigned short*)(smem + 32768);   // [2][128][36] (contig [256][36])
    int* const cnt  = (int*)(smem + 51200);                         // [2][128]
    int* const ctr  = (int*)(smem + 52224);                         // [2][128]
    int* const cnti = (int*)(smem + 53248);                         // [2][32]
    int* const wtot = (int*)(smem + 53504);                         // [2]
    unsigned short* const xs16 = (unsigned short*)smem;             // [2][128][72] ([256][72])
    unsigned short* const sT   = (unsigned short*)(smem + 36864);   // [2][32][132] ([64][132])
    unsigned short* const HT   = (unsigned short*)smem;             // [2][64][136] ([128][136])
    unsigned short* const xs3  = (unsigned short*)smem;             // [2][32][168] ([64][168])
    unsigned short* const agg2 = (unsigned short*)(smem + 36864);   // [2][32][72] ([64][72])
    float* const red  = (float*)(smem + 36864);                     // [2][128][9] ([256][9])
    float* const invc = (float*)(smem + 53760);                     // [2][32]

    // ---- F0: zero counters, per-cluster rel/slc (split by thread half), aggT K-pads ----
    cnt[t] = 0;                       // 2*128 == 256
    if (t < 64) cnti[t] = 0;          // 2*32
    int slc_r; float relx, rely, relz;
    {
        const int gm = g0 + myg;
        const int c2 = idx1[gm*CPG_ + th];
        slc_r = c2 - gm*CPG2_;
        relx = pos1[(gm*CPG_ + th)*3 + 0] - pos2[c2*3 + 0];
        rely = pos1[(gm*CPG_ + th)*3 + 1] - pos2[c2*3 + 1];
        relz = pos1[(gm*CPG_ + th)*3 + 2] - pos2[c2*3 + 2];
    }
    for (int i = t; i < 256*8; i += 256) {     // aggT K-pad cols 16..31, both glimpses
        const int r = i >> 3, j = i & 7;
        ((unsigned*)aggT)[r*18 + 8 + j] = 0u;
    }
    __syncthreads();   // B0

    // ---- F1: load 2x2 points raw + counts ----
    float px0[2][2], prx[2][2], pry[2][2], prz[2][2];
    int plc[2][2];
    #pragma unroll
    for (int gi = 0; gi < 2; gi++)
    #pragma unroll
    for (int r = 0; r < 2; r++) {
        const int p = (g0 + gi)*NPG_ + r*256 + t;
        const int c = idx0[p];
        plc[gi][r] = c - (g0 + gi)*CPG_;
        px0[gi][r] = rgb[p];
        prx[gi][r] = pos[p*3+0] - pos1[c*3+0];
        pry[gi][r] = pos[p*3+1] - pos1[c*3+1];
        prz[gi][r] = pos[p*3+2] - pos1[c*3+2];
        atomicAdd(&cnt[gi*128 + plc[gi][r]], 1);
    }
    atomicAdd(&cnti[myg*32 + slc_r], 1);
    __syncthreads();   // B1

    // ---- F2: parallel scans (waves 0-1 -> A, waves 2-3 -> B) + invc ----
    {
        const int v0 = cnt[myg*128 + th];
        int val = v0;
        const int ln = t & 63;
        #pragma unroll
        for (int d = 1; d < 64; d <<= 1) {
            const int v = __shfl_up(val, d, 64);
            if (ln >= d) val += v;
        }
        ctr[myg*128 + th] = val - v0;           // wave-local exclusive
        if ((t & 127) == 63) wtot[myg] = val;   // first-half total per glimpse
    }
    if (t < 64) invc[t] = 1.f / fmaxf((float)cnti[t], 1.f);
    __syncthreads();   // B2

    const int wt0 = wtot[0], wt1 = wtot[1];     // LDS broadcast reads

    // ---- F3: per-point MLP in f32 -> packed fp16 -> uint4 plane scatter (4 points) ----
    #pragma unroll
    for (int gi = 0; gi < 2; gi++) {
        const int wtg = gi ? wt1 : wt0;
        #pragma unroll
        for (int r = 0; r < 2; r++) {
            unsigned hpk[8];
            #pragma unroll
            for (int j = 0; j < 16; j += 2) {
                const float h0 = celu_f(b1l[j]   + px0[gi][r]*W1l[j]   + prx[gi][r]*W1l[16+j]
                                                  + pry[gi][r]*W1l[32+j]   + prz[gi][r]*W1l[48+j]);
                const float h1 = celu_f(b1l[j+1] + px0[gi][r]*W1l[j+1] + prx[gi][r]*W1l[16+j+1]
                                                  + pry[gi][r]*W1l[32+j+1] + prz[gi][r]*W1l[48+j+1]);
                union { f16x2 h; unsigned u; } pk;
                pk.h[0] = (_Float16)h0;   // RNE
                pk.h[1] = (_Float16)h1;
                hpk[j >> 1] = pk.u;
            }
            const int pc = plc[gi][r];
            const int slot = atomicAdd(&ctr[gi*128 + pc], 1) + (pc >= 64 ? wtg : 0);
            uint4 q0, q1;
            q0.x = hpk[0]; q0.y = hpk[1]; q0.z = hpk[2]; q0.w = hpk[3];
            q1.x = hpk[4]; q1.y = hpk[5]; q1.z = hpk[6]; q1.w = hpk[7];
            hp4[gi*1024 + slot]       = q0;
            hp4[gi*1024 + 512 + slot] = q1;
        }
    }
    __syncthreads();   // B3

    // w1g fragments: latency hides under the serial reduce
    const bf16x8 w1g_b0 = *(const bf16x8*)&w1gT[lr*40 + quad*8];
    const bf16x8 w1g_b1 = *(const bf16x8*)&w1gT[(16 + lr)*40 + quad*8];
    const float  b1g_0 = b1g[lr], b1g_1 = b1g[16 + lr];

    // ---- F4: pk_f16 segment reduction (both glimpses), 2 threads/cluster ----
    {
        const int c = t >> 1, half = t & 1;
        const int ch0 = half * 8, j0 = half * 4;
        #pragma unroll
        for (int gi = 0; gi < 2; gi++) {
            const int n = cnt[gi*128 + c];
            const int wtg = gi ? wt1 : wt0;
            const int base = ctr[gi*128 + c] - n + (c >= 64 ? wtg : 0);
            const int n0 = (n + 1) >> 1;
            const int sI = base + (half ? n0 : 0);
            const int eI = base + (half ? n  : n0);
            f16x2 acc[8];
            #pragma unroll
            for (int j = 0; j < 8; j++) { union { unsigned u; f16x2 h; } z; z.u = 0u; acc[j] = z.h; }
            for (int i = sI; i < eI; i++) {
                const uint4 a = hp4[gi*1024 + i];
                const uint4 b = hp4[gi*1024 + 512 + i];
                union { unsigned u; f16x2 h; } w;
                w.u = a.x; acc[0] += w.h;  w.u = a.y; acc[1] += w.h;
                w.u = a.z; acc[2] += w.h;  w.u = a.w; acc[3] += w.h;
                w.u = b.x; acc[4] += w.h;  w.u = b.y; acc[5] += w.h;
                w.u = b.z; acc[6] += w.h;  w.u = b.w; acc[7] += w.h;
            }
            #pragma unroll
            for (int j = 0; j < 8; j++) {      // pair-combine lanes 2c/2c+1
                union { unsigned u; f16x2 h; } s, o;
                s.h = acc[j];
                o.u = __shfl_xor(s.u, 1);
                acc[j] += o.h;
            }
            const float inv = 1.f / fmaxf((float)n, 1.f);
            float v[8];
            #pragma unroll
            for (int k = 0; k < 4; k++) {
                v[2*k]   = (float)acc[j0+k][0] * inv;
                v[2*k+1] = (float)acc[j0+k][1] * inv;
            }
            uint2 q0, q1;
            q0.x = pack2(v[0], v[1]); q0.y = pack2(v[2], v[3]);
            q1.x = pack2(v[4], v[5]); q1.y = pack2(v[6], v[7]);
            *(uint2*)&aggT[(gi*128 + c)*36 + ch0]     = q0;
            *(uint2*)&aggT[(gi*128 + c)*36 + ch0 + 4] = q1;
        }
    }
    __syncthreads();   // B4

    // ---- F5: conv1 global MFMA, both glimpses -> c1 regs ----
    f32x4 c1[2][2][2];    // [gi][nt][mt]
    #pragma unroll
    for (int gi = 0; gi < 2; gi++) {
        c1[gi][0][0] = (f32x4){b1g_0, b1g_0, b1g_0, b1g_0};
        c1[gi][0][1] = c1[gi][0][0];
        c1[gi][1][0] = (f32x4){b1g_1, b1g_1, b1g_1, b1g_1};
        c1[gi][1][1] = c1[gi][1][0];
        #pragma unroll
        for (int mt = 0; mt < 2; mt++) {
            const bf16x8 a = ldb8(&aggT[(gi*128 + (2*wv + mt)*16 + lr)*36 + quad*8]);
            c1[gi][0][mt] = __builtin_amdgcn_mfma_f32_16x16x32_bf16(a, w1g_b0, c1[gi][0][mt], 0, 0, 0);
            c1[gi][1][mt] = __builtin_amdgcn_mfma_f32_16x16x32_bf16(a, w1g_b1, c1[gi][1][mt], 0, 0, 0);
        }
    }
    __syncthreads();   // B5 (hp4/aggT/counters dead -> xs16/sT)

    // ---- F6: xs16 fills (f1, relpos, pads) both glimpses + sT zero ----
    {
        const uint4 z4 = {0u, 0u, 0u, 0u};
        for (int i = t; i < 1056; i += 256) ((uint4*)sT)[i] = z4;   // 2*32*132 us = 16896 B
        for (int i = t; i < 256*5; i += 256) {                      // cols 35..39
            const int r = i / 5, c = 35 + (i - r*5);
            xs16[r*72 + c] = 0;
        }
        for (int i = t; i < 256*3; i += 256) {                      // cols 40..63
            const int r = i / 3, c4 = i - r*3;
            *(uint4*)&xs16[r*72 + 40 + c4*8] = z4;
        }
    }
    #pragma unroll
    for (int gi = 0; gi < 2; gi++)
    #pragma unroll
    for (int nt = 0; nt < 2; nt++)
    #pragma unroll
    for (int mt = 0; mt < 2; mt++)
    #pragma unroll
    for (int r = 0; r < 4; r++) {
        const int cl = (2*wv + mt)*16 + quad*4 + r;
        xs16[(gi*128 + cl)*72 + nt*16 + lr] = f2bf(celu_f(c1[gi][nt][mt][r]));
    }
    xs16[(myg*128 + th)*72 + 32] = f2bf(relx);
    xs16[(myg*128 + th)*72 + 33] = f2bf(rely);
    xs16[(myg*128 + th)*72 + 34] = f2bf(relz);
    __syncthreads();   // B6

    // ---- F7: one-hot scatter (both) + conv2 local A ----
    sT[(myg*32 + slc_r)*132 + th] = 0x3F80;   // bf16 1.0
    const int chn = wv*16 + lr;
    const bf16x8 bw2l0 = *(const bf16x8*)&w2lT[chn*64 + quad*8];
    const bf16x8 bw2l1 = *(const bf16x8*)&w2lT[chn*64 + 32 + quad*8];
    const float  b2lv  = b2l[chn];
    float hv[8][4];
    #pragma unroll
    for (int m = 0; m < 8; m++) {
        f32x4 acc = (f32x4){b2lv, b2lv, b2lv, b2lv};
        const bf16x8 a0 = *(const bf16x8*)&xs16[(m*16 + lr)*72 + quad*8];
        const bf16x8 a1 = *(const bf16x8*)&xs16[(m*16 + lr)*72 + 32 + quad*8];
        acc = __builtin_amdgcn_mfma_f32_16x16x32_bf16(a0, bw2l0, acc, 0, 0, 0);
        acc = __builtin_amdgcn_mfma_f32_16x16x32_bf16(a1, bw2l1, acc, 0, 0, 0);
        #pragma unroll
        for (int r = 0; r < 4; r++) hv[m][r] = celu_f(acc[r]);
    }
    __syncthreads();   // B7

    // ---- F8: store HT_A + conv2 local B ----
    #pragma unroll
    for (int m = 0; m < 8; m++) {
        uint2 p;
        p.x = pack2(hv[m][0], hv[m][1]);
        p.y = pack2(hv[m][2], hv[m][3]);
        *(uint2*)&HT[chn*136 + m*16 + quad*4] = p;
    }
    #pragma unroll
    for (int m = 0; m < 8; m++) {
        f32x4 acc = (f32x4){b2lv, b2lv, b2lv, b2lv};
        const bf16x8 a0 = *(const bf16x8*)&xs16[(128 + m*16 + lr)*72 + quad*8];
        const bf16x8 a1 = *(const bf16x8*)&xs16[(128 + m*16 + lr)*72 + 32 + quad*8];
        acc = __builtin_amdgcn_mfma_f32_16x16x32_bf16(a0, bw2l0, acc, 0, 0, 0);
        acc = __builtin_amdgcn_mfma_f32_16x16x32_bf16(a1, bw2l1, acc, 0, 0, 0);
        #pragma unroll
        for (int r = 0; r < 4; r++) hv[m][r] = celu_f(acc[r]);
    }
    __syncthreads();   // B8

    // ---- F9: store HT_B + segment-sum MFMA A ----
    #pragma unroll
    for (int m = 0; m < 8; m++) {
        uint2 p;
        p.x = pack2(hv[m][0], hv[m][1]);
        p.y = pack2(hv[m][2], hv[m][3]);
        *(uint2*)&HT[(64 + chn)*136 + m*16 + quad*4] = p;
    }
    float aggv[2][4];
    {
        f32x4 acc[2];
        acc[0] = (f32x4){0.f, 0.f, 0.f, 0.f};
        acc[1] = (f32x4){0.f, 0.f, 0.f, 0.f};
        #pragma unroll
        for (int ks = 0; ks < 4; ks++) {
            const bf16x8 b = *(const bf16x8*)&HT[chn*136 + ks*32 + quad*8];
            #pragma unroll
            for (int mt = 0; mt < 2; mt++) {
                const bf16x8 a = ldb8(&sT[(mt*16 + lr)*132 + ks*32 + quad*8]);
                acc[mt] = __builtin_amdgcn_mfma_f32_16x16x32_bf16(a, b, acc[mt], 0, 0, 0);
            }
        }
        #pragma unroll
        for (int mt = 0; mt < 2; mt++)
        #pragma unroll
        for (int r = 0; r < 4; r++)
            aggv[mt][r] = acc[mt][r] * invc[mt*16 + quad*4 + r];
    }
    __syncthreads();   // B9

    // ---- F10: agg2_A stores + xs3_A rel/pads + segment-sum MFMA B ----
    #pragma unroll
    for (int mt = 0; mt < 2; mt++)
    #pragma unroll
    for (int r = 0; r < 4; r++)
        agg2[(mt*16 + quad*4 + r)*72 + chn] = f2bf(aggv[mt][r]);
    if (t < CPG2_) {
        #pragma unroll
        for (int d = 0; d < 3; d++)
            xs3[t*168 + 128 + d] = f2bf(pos2[(g0*CPG2_ + t)*3 + d]);
    }
    {
        const uint4 z4 = {0u, 0u, 0u, 0u};
        for (int i = t; i < 32*5; i += 256) {
            const int r = i / 5, c = 131 + (i - r*5);
            xs3[r*168 + c] = 0;
        }
        for (int i = t; i < 32*3; i += 256) {
            const int r = i / 3, c4 = i - r*3;
            *(uint4*)&xs3[r*168 + 136 + c4*8] = z4;
        }
    }
    {
        f32x4 acc[2];
        acc[0] = (f32x4){0.f, 0.f, 0.f, 0.f};
        acc[1] = (f32x4){0.f, 0.f, 0.f, 0.f};
        #pragma unroll
        for (int ks = 0; ks < 4; ks++) {
            const bf16x8 b = *(const bf16x8*)&HT[(64 + chn)*136 + ks*32 + quad*8];
            #pragma unroll
            for (int mt = 0; mt < 2; mt++) {
                const bf16x8 a = ldb8(&sT[(32 + mt*16 + lr)*132 + ks*32 + quad*8]);
                acc[mt] = __builtin_amdgcn_mfma_f32_16x16x32_bf16(a, b, acc[mt], 0, 0, 0);
            }
        }
        #pragma unroll
        for (int mt = 0; mt < 2; mt++)
        #pragma unroll
        for (int r = 0; r < 4; r++)
            aggv[mt][r] = acc[mt][r] * invc[32 + mt*16 + quad*4 + r];
    }
    __syncthreads();   // B10

    // ---- F11: agg2_B stores + xs3_B rel/pads + conv2 global A ----
    #pragma unroll
    for (int mt = 0; mt < 2; mt++)
    #pragma unroll
    for (int r = 0; r < 4; r++)
        agg2[(32 + mt*16 + quad*4 + r)*72 + chn] = f2bf(aggv[mt][r]);
    if (t < CPG2_) {
        #pragma unroll
        for (int d = 0; d < 3; d++)
            xs3[(32 + t)*168 + 128 + d] = f2bf(pos2[((g0 + 1)*CPG2_ + t)*3 + d]);
    }
    {
        const uint4 z4 = {0u, 0u, 0u, 0u};
        for (int i = t; i < 32*5; i += 256) {
            const int r = i / 5, c = 131 + (i - r*5);
            xs3[(32 + r)*168 + c] = 0;
        }
        for (int i = t; i < 32*3; i += 256) {
            const int r = i / 3, c4 = i - r*3;
            *(uint4*)&xs3[(32 + r)*168 + 136 + c4*8] = z4;
        }
    }
    int chn2[2];
    bf16x8 bw2g[2][2];
    float b2gv[2];
    #pragma unroll
    for (int nt = 0; nt < 2; nt++) {
        chn2[nt] = (wv + nt*4)*16 + lr;
        b2gv[nt] = b2g[chn2[nt]];
        bw2g[nt][0] = *(const bf16x8*)&w2gT[chn2[nt]*64 + quad*8];
        bw2g[nt][1] = *(const bf16x8*)&w2gT[chn2[nt]*64 + 32 + quad*8];
    }
    {
        f32x4 acc2[2][2];
        #pragma unroll
        for (int nt = 0; nt < 2; nt++)
        #pragma unroll
        for (int mt = 0; mt < 2; mt++) acc2[nt][mt] = (f32x4){b2gv[nt], b2gv[nt], b2gv[nt], b2gv[nt]};
        #pragma unroll
        for (int ks = 0; ks < 2; ks++) {
            #pragma unroll
            for (int mt = 0; mt < 2; mt++) {
                const bf16x8 a = *(const bf16x8*)&agg2[(mt*16 + lr)*72 + ks*32 + quad*8];
                acc2[0][mt] = __builtin_amdgcn_mfma_f32_16x16x32_bf16(a, bw2g[0][ks], acc2[0][mt], 0, 0, 0);
                acc2[1][mt] = __builtin_amdgcn_mfma_f32_16x16x32_bf16(a, bw2g[1][ks], acc2[1][mt], 0, 0, 0);
            }
        }
        #pragma unroll
        for (int nt = 0; nt < 2; nt++)
        #pragma unroll
        for (int mt = 0; mt < 2; mt++)
        #pragma unroll
        for (int r = 0; r < 4; r++) {
            const int row = mt*16 + quad*4 + r;
            xs3[row*168 + chn2[nt]] = f2bf(celu_f(acc2[nt][mt][r]));
        }
    }
    __syncthreads();   // B11

    // ---- F12: conv2 global B + conv3 local A ----
    {
        f32x4 acc2[2][2];
        #pragma unroll
        for (int nt = 0; nt < 2; nt++)
        #pragma unroll
        for (int mt = 0; mt < 2; mt++) acc2[nt][mt] = (f32x4){b2gv[nt], b2gv[nt], b2gv[nt], b2gv[nt]};
        #pragma unroll
        for (int ks = 0; ks < 2; ks++) {
            #pragma unroll
            for (int mt = 0; mt < 2; mt++) {
                const bf16x8 a = *(const bf16x8*)&agg2[(32 + mt*16 + lr)*72 + ks*32 + quad*8];
                acc2[0][mt] = __builtin_amdgcn_mfma_f32_16x16x32_bf16(a, bw2g[0][ks], acc2[0][mt], 0, 0, 0);
                acc2[1][mt] = __builtin_amdgcn_mfma_f32_16x16x32_bf16(a, bw2g[1][ks], acc2[1][mt], 0, 0, 0);
            }
        }
        #pragma unroll
        for (int nt = 0; nt < 2; nt++)
        #pragma unroll
        for (int mt = 0; mt < 2; mt++)
        #pragma unroll
        for (int r = 0; r < 4; r++) {
            const int row = mt*16 + quad*4 + r;
            xs3[(32 + row)*168 + chn2[nt]] = f2bf(celu_f(acc2[nt][mt][r]));
        }
    }
    const float b3lv[2] = {b3l[chn2[0]], b3l[chn2[1]]};
    {
        f32x4 acc[2][2];
        #pragma unroll
        for (int nt = 0; nt < 2; nt++)
        #pragma unroll
        for (int mt = 0; mt < 2; mt++) acc[nt][mt] = (f32x4){b3lv[nt], b3lv[nt], b3lv[nt], b3lv[nt]};
        #pragma unroll
        for (int ks = 0; ks < 5; ks++) {
            const bf16x8 b0 = *(const bf16x8*)&w3lT[chn2[0]*160 + ks*32 + quad*8];
            const bf16x8 b1 = *(const bf16x8*)&w3lT[chn2[1]*160 + ks*32 + quad*8];
            #pragma unroll
            for (int mt = 0; mt < 2; mt++) {
                const bf16x8 a = *(const bf16x8*)&xs3[(mt*16 + lr)*168 + ks*32 + quad*8];
                acc[0][mt] = __builtin_amdgcn_mfma_f32_16x16x32_bf16(a, b0, acc[0][mt], 0, 0, 0);
                acc[1][mt] = __builtin_amdgcn_mfma_f32_16x16x32_bf16(a, b1, acc[1][mt], 0, 0, 0);
            }
        }
        #pragma unroll
        for (int nt = 0; nt < 2; nt++)
        #pragma unroll
        for (int mt = 0; mt < 2; mt++) {
            const float p = celu_f(acc[nt][mt][0]) + celu_f(acc[nt][mt][1])
                          + celu_f(acc[nt][mt][2]) + celu_f(acc[nt][mt][3]);
            red[chn2[nt]*9 + mt*4 + quad] = p;
        }
    }
    __syncthreads();   // B12

    // ---- F13: conv3 local B + mean A ----
    {
        f32x4 acc[2][2];
        #pragma unroll
        for (int nt = 0; nt < 2; nt++)
        #pragma unroll
        for (int mt = 0; mt < 2; mt++) acc[nt][mt] = (f32x4){b3lv[nt], b3lv[nt], b3lv[nt], b3lv[nt]};
        #pragma unroll
        for (int ks = 0; ks < 5; ks++) {
            const bf16x8 b0 = *(const bf16x8*)&w3lT[chn2[0]*160 + ks*32 + quad*8];
            const bf16x8 b1 = *(const bf16x8*)&w3lT[chn2[1]*160 + ks*32 + quad*8];
            #pragma unroll
            for (int mt = 0; mt < 2; mt++) {
                const bf16x8 a = *(const bf16x8*)&xs3[(32 + mt*16 + lr)*168 + ks*32 + quad*8];
                acc[0][mt] = __builtin_amdgcn_mfma_f32_16x16x32_bf16(a, b0, acc[0][mt], 0, 0, 0);
                acc[1][mt] = __builtin_amdgcn_mfma_f32_16x16x32_bf16(a, b1, acc[1][mt], 0, 0, 0);
            }
        }
        #pragma unroll
        for (int nt = 0; nt < 2; nt++)
        #pragma unroll
        for (int mt = 0; mt < 2; mt++) {
            const float p = celu_f(acc[nt][mt][0]) + celu_f(acc[nt][mt][1])
                          + celu_f(acc[nt][mt][2]) + celu_f(acc[nt][mt][3]);
            red[(128 + chn2[nt])*9 + mt*4 + quad] = p;
        }
    }
    if (t < 128) {
        const float* rp = &red[t*9];
        float a = 0.f;
        #pragma unroll
        for (int p = 0; p < 8; p++) a += rp[p];
        aggws[(size_t)g0*128 + t] = f2bf(a * (1.f/32.f));
    }
    __syncthreads();   // B13

    // ---- F14: mean B ----
    if (t < 128) {
        const float* rp = &red[(128 + t)*9];
        float a = 0.f;
        #pragma unroll
        for (int p = 0; p < 8; p++) a += rp[p];
        aggws[(size_t)(g0 + 1)*128 + t] = f2bf(a * (1.f/32.f));
    }
}

// ============== head: 16 glimpses per block; z/mu/sigma from paired accumulators ==============
__global__ __launch_bounds__(256) void k_head(
    const unsigned short* __restrict__ aggws,
    const unsigned short* __restrict__ w3gT, const float* __restrict__ b3g,
    const unsigned short* __restrict__ wlinT, const float* __restrict__ blin,
    const float* __restrict__ eps, float* __restrict__ out)
{
    const int g0 = blockIdx.x * 16, t = threadIdx.x;
    const int lane = t & 63, wv = t >> 6;
    const int lr = lane & 15, quad = lane >> 4;
    __shared__ __align__(16) unsigned short aggB[16*136];
    __shared__ __align__(16) unsigned short f3B[16*264];

    {   // stage agg rows: 256 uint4
        const int row = t >> 4, col8 = (t & 15) * 8;
        const uint4 v = ((const uint4*)aggws)[(size_t)g0*16 + t];
        *(uint4*)&aggB[row*136 + col8] = v;
    }
    __syncthreads();

    // W3g MFMA: C[16 glimpses][256] = aggB @ W3g
    {
        f32x4 c3[4];
        int ch3[4];
        #pragma unroll
        for (int nt = 0; nt < 4; nt++) {
            ch3[nt] = (wv + nt*4)*16 + lr;
            const float bias = b3g[ch3[nt]];
            c3[nt] = (f32x4){bias, bias, bias, bias};
        }
        #pragma unroll
        for (int ks = 0; ks < 4; ks++) {
            const bf16x8 a = *(const bf16x8*)&aggB[lr*136 + ks*32 + quad*8];
            #pragma unroll
            for (int nt = 0; nt < 4; nt++) {
                const bf16x8 b = *(const bf16x8*)&w3gT[ch3[nt]*128 + ks*32 + quad*8];
                c3[nt] = __builtin_amdgcn_mfma_f32_16x16x32_bf16(a, b, c3[nt], 0, 0, 0);
            }
        }
        #pragma unroll
        for (int nt = 0; nt < 4; nt++)
        #pragma unroll
        for (int r = 0; r < 4; r++) {
            const int row = quad*4 + r;
            const float v = celu_f(c3[nt][r]);
            out[OFF_F + (size_t)(g0 + row)*256 + ch3[nt]] = v;
            f3B[row*264 + ch3[nt]] = f2bf(v);
        }
    }
    __syncthreads();

    // Wlin MFMA: C[16][256] = f3B @ Wlin; sample in-register (lane owns ch and ch+128)
    {
        f32x4 cl[4];
        int ch4[4];
        #pragma unroll
        for (int nt = 0; nt < 4; nt++) {
            ch4[nt] = (wv + nt*4)*16 + lr;
            const float bias = blin[ch4[nt]];
            cl[nt] = (f32x4){bias, bias, bias, bias};
        }
        #pragma unroll
        for (int ks = 0; ks < 8; ks++) {
            const bf16x8 a = *(const bf16x8*)&f3B[lr*264 + ks*32 + quad*8];
            #pragma unroll
            for (int nt = 0; nt < 4; nt++) {
                const bf16x8 b = *(const bf16x8*)&wlinT[ch4[nt]*256 + ks*32 + quad*8];
                cl[nt] = __builtin_amdgcn_mfma_f32_16x16x32_bf16(a, b, cl[nt], 0, 0, 0);
            }
        }
        // nt and nt+2 share the lane: ch4[nt+2] == ch4[nt] + 128
        #pragma unroll
        for (int nt = 0; nt < 2; nt++)
        #pragma unroll
        for (int r = 0; r < 4; r++) {
            const int row = quad*4 + r;
            const int g = g0 + row;
            const int ch = ch4[nt];                 // 0..127
            const float mu    = cl[nt][r];
            const float sigma = softplus_f(cl[nt + 2][r]);
            const float z     = mu + sigma * eps[(size_t)g*128 + ch];
            out[OFF_MU + (size_t)g*128 + ch] = mu;
            out[OFF_SG + (size_t)g*128 + ch] = sigma;
            if (nt == 0) out[OFF_ZW + (size_t)g*64 + ch] = z;          // ch in [0,64)
            else         out[OFF_ZM + (size_t)g*64 + (ch - 64)] = z;   // ch in [64,128)
        }
    }
}

extern "C" void kernel_launch(void* const* d_in, const int* in_sizes, int n_in,
                              void* d_out, int out_size, void* d_ws, size_t ws_size,
                              hipStream_t stream)
{
    const float* rgb  = (const float*)d_in[0];
    const float* pos  = (const float*)d_in[1];
    const float* pos1 = (const float*)d_in[2];
    const float* pos2 = (const float*)d_in[3];
    const int*   idx0 = (const int*)d_in[4];
    const int*   idx1 = (const int*)d_in[5];
    const float* eps  = (const float*)d_in[7];
    const float* W1l = (const float*)d_in[8],  *b1l = (const float*)d_in[9];
    const float* W1g = (const float*)d_in[10], *b1g = (const float*)d_in[11];
    const float* W2l = (const float*)d_in[12], *b2l = (const float*)d_in[13];
    const float* W2g = (const float*)d_in[14], *b2g = (const float*)d_in[15];
    const float* W3l = (const float*)d_in[16], *b3l = (const float*)d_in[17];
    const float* W3g = (const float*)d_in[18], *b3g = (const float*)d_in[19];
    const float* Wlin = (const float*)d_in[20], *blin = (const float*)d_in[21];

    unsigned short* w2lT  = (unsigned short*)d_ws;       // 64*64
    unsigned short* w2gT  = w2lT + 64*64;                // 128*64
    unsigned short* w3lT  = w2gT + 128*64;               // 128*160
    unsigned short* w3gT  = w3lT + 128*160;              // 256*128
    unsigned short* wlinT = w3gT + 256*128;              // 256*256
    unsigned short* w1gT  = wlinT + 256*256;             // 32*40
    unsigned short* aggws = w1gT + 32*40;                // G*128 bf16
    float* outp = (float*)d_out;

    k_prep <<<64,    256, 0, stream>>>(W2l, W2g, W3l, W3g, Wlin, W1g,
                                       w2lT, w2gT, w3lT, w3gT, wlinT, w1gT);
    k_fused<<<G_/2,  256, 0, stream>>>(rgb, pos, pos1, pos2, idx0, idx1,
                                       W1l, b1l, w1gT, b1g,
                                       w2lT, b2l, w2gT, b2g, w3lT, b3l, aggws);
    k_head <<<G_/16, 256, 0, stream>>>(aggws, w3gT, b3g, wlinT, blin, eps, outp);
}

// Round 6
// 152.192 us; speedup vs baseline: 1.0434x; 1.0434x over previous
//
#include <hip/hip_runtime.h>
#include <hip/hip_bf16.h>
#include <cstddef>

#define G_   2048
#define NPG_ 512
#define CPG_ 128
#define CPG2_ 32

// output layout (floats): z_what[G,64] | z_mask[G,64] | mu[G,128] | sigma[G,128] | f[G,256]
#define OFF_ZW 0
#define OFF_ZM (G_*64)
#define OFF_MU (2*G_*64)
#define OFF_SG (2*G_*64 + G_*128)
#define OFF_F  (2*G_*64 + 2*G_*128)

typedef __attribute__((ext_vector_type(8))) short bf16x8;
typedef __attribute__((ext_vector_type(4))) float f32x4;
typedef _Float16 f16x2 __attribute__((ext_vector_type(2)));

__device__ __forceinline__ float celu_f(float x)     { return x > 0.f ? x : __expf(x) - 1.f; }
__device__ __forceinline__ float softplus_f(float x) { return fmaxf(x, 0.f) + __logf(1.f + __expf(-fabsf(x))); }
// fast RNE fp32->bf16 (finite inputs): identical result to __float2bfloat16
__device__ __forceinline__ unsigned short f2bf(float x) {
    unsigned u = __float_as_uint(x);
    u += 0x7FFFu + ((u >> 16) & 1u);
    return (unsigned short)(u >> 16);
}
__device__ __forceinline__ unsigned pack2(float a, float b) {   // bf16(a) | bf16(b)<<16
    unsigned ua = __float_as_uint(a); ua += 0x7FFFu + ((ua >> 16) & 1u);
    unsigned ub = __float_as_uint(b); ub += 0x7FFFu + ((ub >> 16) & 1u);
    return (ua >> 16) | (ub & 0xFFFF0000u);
}
// 8B-aligned bf16x8 LDS load (for odd-16B row strides)
__device__ __forceinline__ bf16x8 ldb8(const unsigned short* p) {
    union { uint2 u[2]; bf16x8 v; } x;
    x.u[0] = *(const uint2*)p;
    x.u[1] = *(const uint2*)(p + 4);
    return x.v;
}

// ---------------- prep: transposed, zero-K-padded bf16 weight copies in ws ----------------
__global__ void k_prep(const float* __restrict__ W2l, const float* __restrict__ W2g,
                       const float* __restrict__ W3l, const float* __restrict__ W3g,
                       const float* __restrict__ Wlin, const float* __restrict__ W1g,
                       unsigned short* __restrict__ w2lT, unsigned short* __restrict__ w2gT,
                       unsigned short* __restrict__ w3lT, unsigned short* __restrict__ w3gT,
                       unsigned short* __restrict__ wlinT, unsigned short* __restrict__ w1gT)
{
    const int tid = blockIdx.x*256 + threadIdx.x, stride = gridDim.x*256;
    for (int i = tid; i < 64*64; i += stride) {          // W2l [35,64] -> [ch][k=64pad]
        const int ch = i >> 6, k = i & 63;
        w2lT[i] = f2bf(k < 35 ? W2l[k*64 + ch] : 0.f);
    }
    for (int i = tid; i < 128*64; i += stride) {         // W2g [64,128] -> [ch][k]
        const int ch = i >> 6, k = i & 63;
        w2gT[i] = f2bf(W2g[k*128 + ch]);
    }
    for (int i = tid; i < 128*160; i += stride) {        // W3l [131,128] -> [ch][k=160pad]
        const int ch = i / 160, k = i % 160;
        w3lT[i] = f2bf(k < 131 ? W3l[k*128 + ch] : 0.f);
    }
    for (int i = tid; i < 256*128; i += stride) {        // W3g [128,256] -> [ch][k]
        const int ch = i >> 7, k = i & 127;
        w3gT[i] = f2bf(W3g[k*256 + ch]);
    }
    for (int i = tid; i < 256*256; i += stride) {        // Wlin [256,256] -> [ch][k]
        const int ch = i >> 8, k = i & 255;
        wlinT[i] = f2bf(Wlin[k*256 + ch]);
    }
    for (int i = tid; i < 32*40; i += stride) {          // W1g [16,32] -> [ch][k=40pad]
        const int ch = i / 40, k = i % 40;
        w1gT[i] = f2bf(k < 16 ? W1g[k*32 + ch] : 0.f);
    }
}

// ============== fused conv1+conv2+conv3local+mean: one block per glimpse ==============
// R4 structure (best: 6 blocks/CU), with:
//  - all-zero K-pad MFMA fragments synthesized in registers (no LDS backing/fills):
//    aggT [128][20], xs16 [128][40], xs3 [32][136]
//  - conv3 mean via shfl_xor over lane bits 4/5 (red buffer + 2 barriers removed)
// 12 barriers. LDS 25984 B -> 6 blocks/CU. Overlays (byte offsets):
//  front: hp4 uint4[2][512] @0 (16384) | aggT us[128][20] @16384 (5120)
//         | cnt @21504 | ctr @22016 | cnti @22528 | wtot @22656
//  back:  xs16 us[128][40] @0 -> HT us[64][136] @0 -> xs3 us[32][136] @0
//         sT us[32][132] @17408 -> agg2 us[32][72] @17408
//  fixed: invc f32[32] @25856
__global__ __launch_bounds__(256, 6) void k_fused(
    const float* __restrict__ rgb, const float* __restrict__ pos, const float* __restrict__ pos1,
    const float* __restrict__ pos2, const int* __restrict__ idx0, const int* __restrict__ idx1,
    const float* __restrict__ W1l, const float* __restrict__ b1l,
    const unsigned short* __restrict__ w1gT, const float* __restrict__ b1g,
    const unsigned short* __restrict__ w2lT, const float* __restrict__ b2l,
    const unsigned short* __restrict__ w2gT, const float* __restrict__ b2g,
    const unsigned short* __restrict__ w3lT, const float* __restrict__ b3l,
    unsigned short* __restrict__ aggws)
{
    const int g = blockIdx.x, t = threadIdx.x;
    const int lane = t & 63, wv = t >> 6;
    const int lr = lane & 15, quad = lane >> 4;
    const bf16x8 z8 = {0,0,0,0,0,0,0,0};

    __shared__ __align__(16) unsigned char smem[25984];
    uint4* const hp4 = (uint4*)smem;                                // [2][512] uint4
    unsigned short* const aggT = (unsigned short*)(smem + 16384);   // [128][20]
    int* const cnt  = (int*)(smem + 21504);                         // [128]
    int* const ctr  = (int*)(smem + 22016);                         // [128]
    int* const cnti = (int*)(smem + 22528);                         // [32]
    int* const wtot = (int*)(smem + 22656);                         // [1]
    unsigned short* const xs16 = (unsigned short*)smem;             // [128][40]
    unsigned short* const HT   = (unsigned short*)smem;             // [64][136]
    unsigned short* const xs3  = (unsigned short*)smem;             // [32][136]
    unsigned short* const sT   = (unsigned short*)(smem + 17408);   // [32][132]
    unsigned short* const agg2 = (unsigned short*)(smem + 17408);   // [32][72]
    float* const invc = (float*)(smem + 25856);                     // [32]

    // ---- pre-B0: counters, slc/rel into regs ----
    if (t < CPG_)  cnt[t]  = 0;
    if (t < CPG2_) cnti[t] = 0;
    int slc_r = 0;
    float relx = 0.f, rely = 0.f, relz = 0.f;
    if (t < CPG_) {
        const int c2 = idx1[g*CPG_ + t];
        slc_r = c2 - g*CPG2_;
        relx = pos1[(g*CPG_ + t)*3 + 0] - pos2[c2*3 + 0];
        rely = pos1[(g*CPG_ + t)*3 + 1] - pos2[c2*3 + 1];
        relz = pos1[(g*CPG_ + t)*3 + 2] - pos2[c2*3 + 2];
    }
    __syncthreads();   // B0

    // ---- F1: load 2 points raw + counts ----
    float px0[2], prx[2], pry[2], prz[2];
    int plc[2];
    #pragma unroll
    for (int r = 0; r < 2; r++) {
        const int p = g*NPG_ + r*256 + t;
        const int c = idx0[p];
        plc[r] = c - g*CPG_;
        px0[r] = rgb[p];
        prx[r] = pos[p*3+0] - pos1[c*3+0];
        pry[r] = pos[p*3+1] - pos1[c*3+1];
        prz[r] = pos[p*3+2] - pos1[c*3+2];
        atomicAdd(&cnt[plc[r]], 1);
    }
    if (t < CPG_) atomicAdd(&cnti[slc_r], 1);
    __syncthreads();   // B1

    // ---- F2: wave-local exclusive scan into ctr + invc ----
    if (t < CPG_) {
        int val = cnt[t];
        const int ln = t & 63;
        #pragma unroll
        for (int d = 1; d < 64; d <<= 1) {
            const int v = __shfl_up(val, d, 64);
            if (ln >= d) val += v;
        }
        ctr[t] = val - cnt[t];          // exclusive within wave
        if (t == 63) *wtot = val;       // wave-0 total
    }
    if (t < CPG2_) invc[t] = 1.f / fmaxf((float)cnti[t], 1.f);
    __syncthreads();   // B2

    const int wtotv = *wtot;            // LDS broadcast

    // ---- F3: per-point MLP in f32 -> packed fp16 -> 2x uint4 plane scatter ----
    #pragma unroll
    for (int r = 0; r < 2; r++) {
        unsigned hpk[8];
        #pragma unroll
        for (int j = 0; j < 16; j += 2) {
            const float h0 = celu_f(b1l[j]   + px0[r]*W1l[j]   + prx[r]*W1l[16+j]
                                              + pry[r]*W1l[32+j]   + prz[r]*W1l[48+j]);
            const float h1 = celu_f(b1l[j+1] + px0[r]*W1l[j+1] + prx[r]*W1l[16+j+1]
                                              + pry[r]*W1l[32+j+1] + prz[r]*W1l[48+j+1]);
            union { f16x2 h; unsigned u; } pk;
            pk.h[0] = (_Float16)h0;   // RNE
            pk.h[1] = (_Float16)h1;
            hpk[j >> 1] = pk.u;
        }
        const int slot = atomicAdd(&ctr[plc[r]], 1) + (plc[r] >= 64 ? wtotv : 0);
        uint4 q0, q1;
        q0.x = hpk[0]; q0.y = hpk[1]; q0.z = hpk[2]; q0.w = hpk[3];
        q1.x = hpk[4]; q1.y = hpk[5]; q1.z = hpk[6]; q1.w = hpk[7];
        hp4[slot]       = q0;
        hp4[512 + slot] = q1;
    }
    __syncthreads();   // B3

    // w1g fragments: latency hides under the serial reduce
    const bf16x8 w1g_b0 = *(const bf16x8*)&w1gT[lr*40 + quad*8];
    const bf16x8 w1g_b1 = *(const bf16x8*)&w1gT[(16 + lr)*40 + quad*8];
    const float  b1g_0 = b1g[lr], b1g_1 = b1g[16 + lr];

    // ---- F4: pk_f16 segment reduction, 2 threads/cluster split the list ----
    {
        const int c = t >> 1, half = t & 1;
        const int n = cnt[c];
        const int base = ctr[c] - n + (c >= 64 ? wtotv : 0);
        const int n0 = (n + 1) >> 1;
        const int sI = base + (half ? n0 : 0);
        const int eI = base + (half ? n  : n0);
        f16x2 acc[8];
        #pragma unroll
        for (int j = 0; j < 8; j++) { union { unsigned u; f16x2 h; } z; z.u = 0u; acc[j] = z.h; }
        for (int i = sI; i < eI; i++) {
            const uint4 a = hp4[i];
            const uint4 b = hp4[512 + i];
            union { unsigned u; f16x2 h; } w;
            w.u = a.x; acc[0] += w.h;  w.u = a.y; acc[1] += w.h;
            w.u = a.z; acc[2] += w.h;  w.u = a.w; acc[3] += w.h;
            w.u = b.x; acc[4] += w.h;  w.u = b.y; acc[5] += w.h;
            w.u = b.z; acc[6] += w.h;  w.u = b.w; acc[7] += w.h;
        }
        #pragma unroll
        for (int j = 0; j < 8; j++) {      // pair-combine lanes 2c/2c+1
            union { unsigned u; f16x2 h; } s, o;
            s.h = acc[j];
            o.u = __shfl_xor(s.u, 1);
            acc[j] += o.h;
        }
        const float inv = 1.f / fmaxf((float)n, 1.f);
        const int ch0 = half * 8, j0 = half * 4;
        float v[8];
        #pragma unroll
        for (int k = 0; k < 4; k++) {
            v[2*k]   = (float)acc[j0+k][0] * inv;
            v[2*k+1] = (float)acc[j0+k][1] * inv;
        }
        uint2 q0, q1;
        q0.x = pack2(v[0], v[1]); q0.y = pack2(v[2], v[3]);
        q1.x = pack2(v[4], v[5]); q1.y = pack2(v[6], v[7]);
        *(uint2*)&aggT[c*20 + ch0]     = q0;
        *(uint2*)&aggT[c*20 + ch0 + 4] = q1;
    }
    __syncthreads();   // B4

    // ---- F5: conv1 global MFMA (K-pad quads 2..3 synthesized as zero regs) ----
    f32x4 c1[2][2];    // [nt][mt]
    {
        c1[0][0] = (f32x4){b1g_0, b1g_0, b1g_0, b1g_0};
        c1[0][1] = c1[0][0];
        c1[1][0] = (f32x4){b1g_1, b1g_1, b1g_1, b1g_1};
        c1[1][1] = c1[1][0];
        #pragma unroll
        for (int mt = 0; mt < 2; mt++) {
            bf16x8 a = z8;
            if (quad < 2) a = ldb8(&aggT[((2*wv + mt)*16 + lr)*20 + quad*8]);
            c1[0][mt] = __builtin_amdgcn_mfma_f32_16x16x32_bf16(a, w1g_b0, c1[0][mt], 0, 0, 0);
            c1[1][mt] = __builtin_amdgcn_mfma_f32_16x16x32_bf16(a, w1g_b1, c1[1][mt], 0, 0, 0);
        }
    }
    __syncthreads();   // B5 (hp4/aggT/counters dead -> xs16/sT)

    // ---- F6: zero sT; xs16: f1 cols 0..31, relpos 32..34, zero 35..39 ----
    {
        const uint4 z4 = {0u, 0u, 0u, 0u};
        for (int i = t; i < 528; i += 256) ((uint4*)sT)[i] = z4;   // 32*132 us
        for (int i = t; i < 128*5; i += 256) {
            const int r = i / 5, c = 35 + (i - r*5);
            xs16[r*40 + c] = 0;
        }
    }
    #pragma unroll
    for (int nt = 0; nt < 2; nt++)
    #pragma unroll
    for (int mt = 0; mt < 2; mt++)
    #pragma unroll
    for (int r = 0; r < 4; r++) {
        const int cl = (2*wv + mt)*16 + quad*4 + r;
        xs16[cl*40 + nt*16 + lr] = f2bf(celu_f(c1[nt][mt][r]));
    }
    if (t < CPG_) {
        xs16[t*40 + 32] = f2bf(relx);
        xs16[t*40 + 33] = f2bf(rely);
        xs16[t*40 + 34] = f2bf(relz);
    }
    __syncthreads();   // B6

    // ---- F7: one-hot scatter into sT; conv2 local MFMA (K 32..63 reg-synthesized) ----
    if (t < CPG_) sT[slc_r*132 + t] = 0x3F80;   // bf16 1.0
    float hv[8][4];
    {
        const int chn = wv*16 + lr;
        const bf16x8 bw0 = *(const bf16x8*)&w2lT[chn*64 + quad*8];
        const bf16x8 bw1 = *(const bf16x8*)&w2lT[chn*64 + 32 + quad*8];
        const float bias = b2l[chn];
        #pragma unroll
        for (int m = 0; m < 8; m++) {
            f32x4 acc = (f32x4){bias, bias, bias, bias};
            const bf16x8 a0 = *(const bf16x8*)&xs16[(m*16 + lr)*40 + quad*8];
            bf16x8 a1 = z8;
            if (quad == 0) a1 = *(const bf16x8*)&xs16[(m*16 + lr)*40 + 32];
            acc = __builtin_amdgcn_mfma_f32_16x16x32_bf16(a0, bw0, acc, 0, 0, 0);
            acc = __builtin_amdgcn_mfma_f32_16x16x32_bf16(a1, bw1, acc, 0, 0, 0);
            #pragma unroll
            for (int r = 0; r < 4; r++) hv[m][r] = celu_f(acc[r]);
        }
    }
    __syncthreads();   // B7 (xs16 dead -> HT)

    // ---- F8: store H^T ----
    {
        const int chn = wv*16 + lr;
        #pragma unroll
        for (int m = 0; m < 8; m++) {
            uint2 p;
            p.x = pack2(hv[m][0], hv[m][1]);
            p.y = pack2(hv[m][2], hv[m][3]);
            *(uint2*)&HT[chn*136 + m*16 + quad*4] = p;
        }
    }
    __syncthreads();   // B8

    // ---- F9: segment-sum MFMA agg[32][64] = S^T @ H ----
    float aggv[2][4];
    {
        const int ch = wv*16 + lr;
        f32x4 acc[2];
        acc[0] = (f32x4){0.f, 0.f, 0.f, 0.f};
        acc[1] = (f32x4){0.f, 0.f, 0.f, 0.f};
        #pragma unroll
        for (int ks = 0; ks < 4; ks++) {
            const bf16x8 b = *(const bf16x8*)&HT[ch*136 + ks*32 + quad*8];
            #pragma unroll
            for (int mt = 0; mt < 2; mt++) {
                const bf16x8 a = ldb8(&sT[(mt*16 + lr)*132 + ks*32 + quad*8]);
                acc[mt] = __builtin_amdgcn_mfma_f32_16x16x32_bf16(a, b, acc[mt], 0, 0, 0);
            }
        }
        #pragma unroll
        for (int mt = 0; mt < 2; mt++)
        #pragma unroll
        for (int r = 0; r < 4; r++)
            aggv[mt][r] = acc[mt][r] * invc[mt*16 + quad*4 + r];
    }
    __syncthreads();   // B9 (sT dead -> agg2; HT dead -> xs3)

    // ---- F10: agg2 stores + xs3 rel (128..130) + zero (131..135) ----
    {
        const int ch = wv*16 + lr;
        #pragma unroll
        for (int mt = 0; mt < 2; mt++)
        #pragma unroll
        for (int r = 0; r < 4; r++)
            agg2[(mt*16 + quad*4 + r)*72 + ch] = f2bf(aggv[mt][r]);
    }
    if (t < CPG2_) {
        #pragma unroll
        for (int d = 0; d < 3; d++)
            xs3[t*136 + 128 + d] = f2bf(pos2[(g*CPG2_ + t)*3 + d]);
    }
    if (t < 160) {
        const int r = t / 5, c = 131 + (t - r*5);
        xs3[r*136 + c] = 0;
    }
    __syncthreads();   // B10

    // ---- F11: conv2 global MFMA -> f2 bf16 into xs3 cols 0..127 ----
    int chn2[2];
    {
        f32x4 acc2[2][2];
        bf16x8 bw[2][2];
        #pragma unroll
        for (int nt = 0; nt < 2; nt++) {
            chn2[nt] = (wv + nt*4)*16 + lr;
            const float bias = b2g[chn2[nt]];
            #pragma unroll
            for (int mt = 0; mt < 2; mt++) acc2[nt][mt] = (f32x4){bias, bias, bias, bias};
            bw[nt][0] = *(const bf16x8*)&w2gT[chn2[nt]*64 + quad*8];
            bw[nt][1] = *(const bf16x8*)&w2gT[chn2[nt]*64 + 32 + quad*8];
        }
        #pragma unroll
        for (int ks = 0; ks < 2; ks++) {
            #pragma unroll
            for (int mt = 0; mt < 2; mt++) {
                const bf16x8 a = *(const bf16x8*)&agg2[(mt*16 + lr)*72 + ks*32 + quad*8];
                acc2[0][mt] = __builtin_amdgcn_mfma_f32_16x16x32_bf16(a, bw[0][ks], acc2[0][mt], 0, 0, 0);
                acc2[1][mt] = __builtin_amdgcn_mfma_f32_16x16x32_bf16(a, bw[1][ks], acc2[1][mt], 0, 0, 0);
            }
        }
        #pragma unroll
        for (int nt = 0; nt < 2; nt++)
        #pragma unroll
        for (int mt = 0; mt < 2; mt++)
        #pragma unroll
        for (int r = 0; r < 4; r++) {
            const int row = mt*16 + quad*4 + r;
            xs3[row*136 + chn2[nt]] = f2bf(celu_f(acc2[nt][mt][r]));
        }
    }
    __syncthreads();   // B11 (agg2 dead)

    // ---- F12: conv3 local MFMA (K-chunk 4 reg-synthesized) + shfl mean -> aggws ----
    {
        f32x4 acc[2][2];
        const float b3lv[2] = {b3l[chn2[0]], b3l[chn2[1]]};
        #pragma unroll
        for (int nt = 0; nt < 2; nt++)
        #pragma unroll
        for (int mt = 0; mt < 2; mt++) acc[nt][mt] = (f32x4){b3lv[nt], b3lv[nt], b3lv[nt], b3lv[nt]};
        #pragma unroll
        for (int ks = 0; ks < 4; ks++) {
            const bf16x8 b0 = *(const bf16x8*)&w3lT[chn2[0]*160 + ks*32 + quad*8];
            const bf16x8 b1 = *(const bf16x8*)&w3lT[chn2[1]*160 + ks*32 + quad*8];
            #pragma unroll
            for (int mt = 0; mt < 2; mt++) {
                const bf16x8 a = *(const bf16x8*)&xs3[(mt*16 + lr)*136 + ks*32 + quad*8];
                acc[0][mt] = __builtin_amdgcn_mfma_f32_16x16x32_bf16(a, b0, acc[0][mt], 0, 0, 0);
                acc[1][mt] = __builtin_amdgcn_mfma_f32_16x16x32_bf16(a, b1, acc[1][mt], 0, 0, 0);
            }
        }
        {   // K-chunk 4 (cols 128..159): only quad0 cols 128..135 real, rest zero
            const bf16x8 b0 = *(const bf16x8*)&w3lT[chn2[0]*160 + 128 + quad*8];
            const bf16x8 b1 = *(const bf16x8*)&w3lT[chn2[1]*160 + 128 + quad*8];
            #pragma unroll
            for (int mt = 0; mt < 2; mt++) {
                bf16x8 a = z8;
                if (quad == 0) a = *(const bf16x8*)&xs3[(mt*16 + lr)*136 + 128];
                acc[0][mt] = __builtin_amdgcn_mfma_f32_16x16x32_bf16(a, b0, acc[0][mt], 0, 0, 0);
                acc[1][mt] = __builtin_amdgcn_mfma_f32_16x16x32_bf16(a, b1, acc[1][mt], 0, 0, 0);
            }
        }
        #pragma unroll
        for (int nt = 0; nt < 2; nt++) {
            float s = 0.f;
            #pragma unroll
            for (int mt = 0; mt < 2; mt++)
                s += celu_f(acc[nt][mt][0]) + celu_f(acc[nt][mt][1])
                   + celu_f(acc[nt][mt][2]) + celu_f(acc[nt][mt][3]);
            s += __shfl_xor(s, 16);
            s += __shfl_xor(s, 32);
            if (quad == 0) aggws[(size_t)g*128 + chn2[nt]] = f2bf(s * (1.f/32.f));
        }
    }
}

// ============== head: 16 glimpses per block, 512 threads (8 waves halve MFMA chain) ==============
__global__ __launch_bounds__(512) void k_head(
    const unsigned short* __restrict__ aggws,
    const unsigned short* __restrict__ w3gT, const float* __restrict__ b3g,
    const unsigned short* __restrict__ wlinT, const float* __restrict__ blin,
    const float* __restrict__ eps, float* __restrict__ out)
{
    const int g0 = blockIdx.x * 16, t = threadIdx.x;
    const int lane = t & 63, wv = t >> 6;          // wv 0..7
    const int lr = lane & 15, quad = lane >> 4;
    __shared__ __align__(16) unsigned short aggB[16*136];
    __shared__ __align__(16) unsigned short f3B[16*264];

    if (t < 256) {   // stage agg rows: 256 uint4
        const int row = t >> 4, col8 = (t & 15) * 8;
        const uint4 v = ((const uint4*)aggws)[(size_t)g0*16 + t];
        *(uint4*)&aggB[row*136 + col8] = v;
    }
    __syncthreads();

    // W3g MFMA: C[16 glimpses][256] = aggB @ W3g  (2 channel-tiles per wave)
    {
        f32x4 c3[2];
        int ch3[2];
        #pragma unroll
        for (int nt = 0; nt < 2; nt++) {
            ch3[nt] = (wv + nt*8)*16 + lr;
            const float bias = b3g[ch3[nt]];
            c3[nt] = (f32x4){bias, bias, bias, bias};
        }
        #pragma unroll
        for (int ks = 0; ks < 4; ks++) {
            const bf16x8 a = *(const bf16x8*)&aggB[lr*136 + ks*32 + quad*8];
            #pragma unroll
            for (int nt = 0; nt < 2; nt++) {
                const bf16x8 b = *(const bf16x8*)&w3gT[ch3[nt]*128 + ks*32 + quad*8];
                c3[nt] = __builtin_amdgcn_mfma_f32_16x16x32_bf16(a, b, c3[nt], 0, 0, 0);
            }
        }
        #pragma unroll
        for (int nt = 0; nt < 2; nt++)
        #pragma unroll
        for (int r = 0; r < 4; r++) {
            const int row = quad*4 + r;
            const float v = celu_f(c3[nt][r]);
            out[OFF_F + (size_t)(g0 + row)*256 + ch3[nt]] = v;
            f3B[row*264 + ch3[nt]] = f2bf(v);
        }
    }
    __syncthreads();

    // Wlin MFMA: C[16][256] = f3B @ Wlin; lane owns ch (nt=0) and ch+128 (nt=1)
    {
        f32x4 cl[2];
        int ch4[2];
        #pragma unroll
        for (int nt = 0; nt < 2; nt++) {
            ch4[nt] = (wv + nt*8)*16 + lr;
            const float bias = blin[ch4[nt]];
            cl[nt] = (f32x4){bias, bias, bias, bias};
        }
        #pragma unroll
        for (int ks = 0; ks < 8; ks++) {
            const bf16x8 a = *(const bf16x8*)&f3B[lr*264 + ks*32 + quad*8];
            #pragma unroll
            for (int nt = 0; nt < 2; nt++) {
                const bf16x8 b = *(const bf16x8*)&wlinT[ch4[nt]*256 + ks*32 + quad*8];
                cl[nt] = __builtin_amdgcn_mfma_f32_16x16x32_bf16(a, b, cl[nt], 0, 0, 0);
            }
        }
        // ch4[1] == ch4[0] + 128: mu from cl[0], sigma-logit from cl[1]
        #pragma unroll
        for (int r = 0; r < 4; r++) {
            const int row = quad*4 + r;
            const int g = g0 + row;
            const int ch = ch4[0];                  // 0..127
            const float mu    = cl[0][r];
            const float sigma = softplus_f(cl[1][r]);
            const float z     = mu + sigma * eps[(size_t)g*128 + ch];
            out[OFF_MU + (size_t)g*128 + ch] = mu;
            out[OFF_SG + (size_t)g*128 + ch] = sigma;
            if (ch < 64) out[OFF_ZW + (size_t)g*64 + ch] = z;
            else         out[OFF_ZM + (size_t)g*64 + (ch - 64)] = z;
        }
    }
}

extern "C" void kernel_launch(void* const* d_in, const int* in_sizes, int n_in,
                              void* d_out, int out_size, void* d_ws, size_t ws_size,
                              hipStream_t stream)
{
    const float* rgb  = (const float*)d_in[0];
    const float* pos  = (const float*)d_in[1];
    const float* pos1 = (const float*)d_in[2];
    const float* pos2 = (const float*)d_in[3];
    const int*   idx0 = (const int*)d_in[4];
    const int*   idx1 = (const int*)d_in[5];
    const float* eps  = (const float*)d_in[7];
    const float* W1l = (const float*)d_in[8],  *b1l = (const float*)d_in[9];
    const float* W1g = (const float*)d_in[10], *b1g = (const float*)d_in[11];
    const float* W2l = (const float*)d_in[12], *b2l = (const float*)d_in[13];
    const float* W2g = (const float*)d_in[14], *b2g = (const float*)d_in[15];
    const float* W3l = (const float*)d_in[16], *b3l = (const float*)d_in[17];
    const float* W3g = (const float*)d_in[18], *b3g = (const float*)d_in[19];
    const float* Wlin = (const float*)d_in[20], *blin = (const float*)d_in[21];

    unsigned short* w2lT  = (unsigned short*)d_ws;       // 64*64
    unsigned short* w2gT  = w2lT + 64*64;                // 128*64
    unsigned short* w3lT  = w2gT + 128*64;               // 128*160
    unsigned short* w3gT  = w3lT + 128*160;              // 256*128
    unsigned short* wlinT = w3gT + 256*128;              // 256*256
    unsigned short* w1gT  = wlinT + 256*256;             // 32*40
    unsigned short* aggws = w1gT + 32*40;                // G*128 bf16
    float* outp = (float*)d_out;

    k_prep <<<64,    256, 0, stream>>>(W2l, W2g, W3l, W3g, Wlin, W1g,
                                       w2lT, w2gT, w3lT, w3gT, wlinT, w1gT);
    k_fused<<<G_,    256, 0, stream>>>(rgb, pos, pos1, pos2, idx0, idx1,
                                       W1l, b1l, w1gT, b1g,
                                       w2lT, b2l, w2gT, b2g, w3lT, b3l, aggws);
    k_head <<<G_/16, 512, 0, stream>>>(aggws, w3gT, b3g, wlinT, blin, eps, outp);
}